// Round 2
// baseline (859.164 us; speedup 1.0000x reference)
//
#include <hip/hip_runtime.h>
#include <hip/hip_bf16.h>

typedef __hip_bfloat16 bf16;
typedef __attribute__((ext_vector_type(8))) short bf16x8v;
typedef __attribute__((ext_vector_type(4))) float f32x4;

namespace {
constexpr int B_  = 2;
constexpr int C_  = 192;
constexpr int HW_ = 128 * 128;   // 16384
constexpr int C2_ = 384;
}

static __device__ __forceinline__ float fb(bf16 v) { return __bfloat162float(v); }
static __device__ __forceinline__ bf16 tob(float v) { return __float2bfloat16(v); }

// ---------------- weight repack: fp32 -> bf16 (optionally zero-padded) ----------------
__global__ void k_repack1(const float* __restrict__ W, bf16* __restrict__ Wr,
                          int N, int K, int Npad, int Kpad) {
    int i = blockIdx.x * 256 + threadIdx.x;
    if (i >= Npad * Kpad) return;
    int n = i / Kpad, k = i % Kpad;
    float v = (n < N && k < K) ? W[n * K + k] : 0.f;
    Wr[i] = tob(v);
}

// W[(n*K+k)*9 + q] -> Wr[(q*Npad + n)*Kpad + k]
__global__ void k_repack3(const float* __restrict__ W, bf16* __restrict__ Wr,
                          int N, int K, int Npad, int Kpad) {
    int i = blockIdx.x * 256 + threadIdx.x;
    if (i >= 9 * Npad * Kpad) return;
    int q = i / (Npad * Kpad);
    int rem = i % (Npad * Kpad);
    int n = rem / Kpad, k = rem % Kpad;
    float v = (n < N && k < K) ? W[(n * K + k) * 9 + q] : 0.f;
    Wr[i] = tob(v);
}

// ---------------- LayerNorm: NCHW fp32 -> [p][c] bf16 ----------------
__global__ __launch_bounds__(256) void k_ln_nchw(const float* __restrict__ X,
                                                 const float* __restrict__ w,
                                                 const float* __restrict__ bb,
                                                 bf16* __restrict__ out) {
    __shared__ float lds[64][C_ + 1];
    int t = threadIdx.x;
    int p0 = blockIdx.x * 64;
    int b = p0 / HW_, pi0 = p0 % HW_;
    for (int i = t; i < 64 * C_; i += 256) {
        int c = i >> 6, pp = i & 63;
        lds[pp][c] = X[((size_t)(b * C_ + c)) * HW_ + pi0 + pp];
    }
    __syncthreads();
    int pp = t >> 2, qq = t & 3;
    float s = 0.f, s2 = 0.f;
    for (int c = qq * 48; c < qq * 48 + 48; c++) { float v = lds[pp][c]; s += v; s2 += v * v; }
    s  += __shfl_xor(s, 1);  s  += __shfl_xor(s, 2);
    s2 += __shfl_xor(s2, 1); s2 += __shfl_xor(s2, 2);
    float mu = s / C_;
    float rstd = rsqrtf(s2 / C_ - mu * mu + 1e-5f);
    size_t ob = ((size_t)(p0 + pp)) * C_;
    for (int c = qq * 48; c < qq * 48 + 48; c++)
        out[ob + c] = tob((lds[pp][c] - mu) * rstd * w[c] + bb[c]);
}

// LayerNorm from [p][c] bf16 -> [p][c] bf16
__global__ __launch_bounds__(256) void k_ln_pc(const bf16* __restrict__ X2,
                                               const float* __restrict__ w,
                                               const float* __restrict__ bb,
                                               bf16* __restrict__ out) {
    int t = threadIdx.x;
    int p = blockIdx.x * 64 + (t >> 2), qq = t & 3;
    const bf16* row = X2 + (size_t)p * C_;
    float s = 0.f, s2 = 0.f;
    for (int c = qq * 48; c < qq * 48 + 48; c++) { float v = fb(row[c]); s += v; s2 += v * v; }
    s  += __shfl_xor(s, 1);  s  += __shfl_xor(s, 2);
    s2 += __shfl_xor(s2, 1); s2 += __shfl_xor(s2, 2);
    float mu = s / C_;
    float rstd = rsqrtf(s2 / C_ - mu * mu + 1e-5f);
    bf16* orow = out + (size_t)p * C_;
    for (int c = qq * 48; c < qq * 48 + 48; c++)
        orow[c] = tob((fb(row[c]) - mu) * rstd * w[c] + bb[c]);
}

// ---------------- 1x1 conv GEMM: D[p][co] = sum_ci A[p][ci]*W[co][ci] ----------------
// EPI: 1 = plain bf16 [p][Cout]
//      2 = +resid(NCHW f32)  -> bf16 [p][C_]
//      3 = +resid(bf16 [p][C_]) -> f32 NCHW
template <int BN, int EPI>
__global__ __launch_bounds__(256) void k_gemm1x1(const bf16* __restrict__ A,
                                                 const bf16* __restrict__ Wr,
                                                 const int K, const int Cout,
                                                 void* __restrict__ outp,
                                                 const void* __restrict__ resid) {
    constexpr int WN = BN / 2, FN = WN / 16, FM = 4;
    __shared__ __align__(16) bf16 As[128 * 36];
    __shared__ __align__(16) bf16 Bs[BN * 36];
    const int t = threadIdx.x;
    const int mt = blockIdx.x;
    const int n0 = blockIdx.y * BN;
    const int w = t >> 6, lane = t & 63;
    const int wm = w >> 1, wn = w & 1;
    const int g = lane >> 4, r = lane & 15;

    f32x4 zz = {0.f, 0.f, 0.f, 0.f};
    f32x4 acc[FM][FN];
#pragma unroll
    for (int i = 0; i < FM; i++)
#pragma unroll
        for (int j = 0; j < FN; j++) acc[i][j] = zz;

    const bf16* Abase = A + (size_t)mt * 128 * K;
    const bf16* Bbase = Wr + (size_t)n0 * K;

    for (int k0 = 0; k0 < K; k0 += 32) {
#pragma unroll
        for (int it = 0; it < 2; it++) {
            int i = t + it * 256;
            int row = i >> 2, c8 = i & 3;
            uint4 v = *(const uint4*)(Abase + (size_t)row * K + k0 + c8 * 8);
            uint2* d = (uint2*)&As[row * 36 + c8 * 8];
            d[0] = make_uint2(v.x, v.y); d[1] = make_uint2(v.z, v.w);
        }
        for (int i = t; i < BN * 4; i += 256) {
            int row = i >> 2, c8 = i & 3;
            uint4 v = *(const uint4*)(Bbase + (size_t)row * K + k0 + c8 * 8);
            uint2* d = (uint2*)&Bs[row * 36 + c8 * 8];
            d[0] = make_uint2(v.x, v.y); d[1] = make_uint2(v.z, v.w);
        }
        __syncthreads();
        bf16x8v af[FM], bfr[FN];
#pragma unroll
        for (int fm = 0; fm < FM; fm++) {
            int row = wm * 64 + fm * 16 + r;
            const uint2* p = (const uint2*)&As[row * 36 + g * 8];
            union { uint2 u[2]; bf16x8v s; } uu; uu.u[0] = p[0]; uu.u[1] = p[1];
            af[fm] = uu.s;
        }
#pragma unroll
        for (int fn = 0; fn < FN; fn++) {
            int row = wn * WN + fn * 16 + r;
            const uint2* p = (const uint2*)&Bs[row * 36 + g * 8];
            union { uint2 u[2]; bf16x8v s; } uu; uu.u[0] = p[0]; uu.u[1] = p[1];
            bfr[fn] = uu.s;
        }
#pragma unroll
        for (int fm = 0; fm < FM; fm++)
#pragma unroll
            for (int fn = 0; fn < FN; fn++)
                acc[fm][fn] = __builtin_amdgcn_mfma_f32_16x16x32_bf16(af[fm], bfr[fn], acc[fm][fn], 0, 0, 0);
        __syncthreads();
    }

    const int b = mt >> 7, y = mt & 127;
#pragma unroll
    for (int fm = 0; fm < FM; fm++)
#pragma unroll
        for (int fn = 0; fn < FN; fn++)
#pragma unroll
            for (int reg = 0; reg < 4; reg++) {
                int xl = wm * 64 + fm * 16 + g * 4 + reg;
                int co = n0 + wn * WN + fn * 16 + r;
                float v = acc[fm][fn][reg];
                if constexpr (EPI == 1) {
                    ((bf16*)outp)[((size_t)mt * 128 + xl) * Cout + co] = tob(v);
                } else if constexpr (EPI == 2) {
                    v += ((const float*)resid)[((size_t)(b * C_ + co)) * HW_ + y * 128 + xl];
                    ((bf16*)outp)[((size_t)mt * 128 + xl) * C_ + co] = tob(v);
                } else {
                    v += fb(((const bf16*)resid)[((size_t)mt * 128 + xl) * C_ + co]);
                    ((float*)outp)[((size_t)(b * C_ + co)) * HW_ + y * 128 + xl] = v;
                }
            }
}

// ---------------- 3x3 full conv as implicit GEMM (unpadded input, predicated borders) ----
// EPI: 0 = plain bf16, 1 = GELU bf16
template <int BN, int EPI>
__global__ __launch_bounds__(256) void k_gemm3x3(const bf16* __restrict__ A,
                                                 const bf16* __restrict__ Wr,
                                                 const int Cin, const int Cout,
                                                 bf16* __restrict__ outp) {
    constexpr int WN = BN / 2, FN = WN / 16, FM = 4;
    __shared__ __align__(16) bf16 As[130 * 36];
    __shared__ __align__(16) bf16 Bs[3 * BN * 36];
    const int t = threadIdx.x;
    const int mt = blockIdx.x;
    const int n0 = blockIdx.y * BN;
    const int b = mt >> 7, y = mt & 127;
    const int w = t >> 6, lane = t & 63;
    const int wm = w >> 1, wn = w & 1;
    const int g = lane >> 4, r = lane & 15;

    f32x4 zz = {0.f, 0.f, 0.f, 0.f};
    f32x4 acc[FM][FN];
#pragma unroll
    for (int i = 0; i < FM; i++)
#pragma unroll
        for (int j = 0; j < FN; j++) acc[i][j] = zz;

    for (int ky = 0; ky < 3; ky++) {
        const int yy = y + ky - 1;
        if (yy < 0 || yy > 127) continue;   // block-uniform
        const bf16* Ab = A + ((size_t)b * HW_ + (size_t)yy * 128) * Cin;
        const bf16* Wb = Wr + (size_t)(ky * 3) * Cout * Cin;
        for (int c0 = 0; c0 < Cin; c0 += 32) {
            for (int i = t; i < 130 * 4; i += 256) {
                int row = i >> 2, c8 = i & 3;
                int xx = row - 1;
                uint4 v = make_uint4(0u, 0u, 0u, 0u);
                if (xx >= 0 && xx < 128)
                    v = *(const uint4*)(Ab + (size_t)xx * Cin + c0 + c8 * 8);
                uint2* d = (uint2*)&As[row * 36 + c8 * 8];
                d[0] = make_uint2(v.x, v.y); d[1] = make_uint2(v.z, v.w);
            }
            for (int i = t; i < 3 * BN * 4; i += 256) {
                int kx = i / (BN * 4);
                int rem = i - kx * (BN * 4);
                int row = rem >> 2, c8 = rem & 3;
                uint4 v = *(const uint4*)(Wb + ((size_t)kx * Cout + n0 + row) * Cin + c0 + c8 * 8);
                uint2* d = (uint2*)&Bs[(kx * BN + row) * 36 + c8 * 8];
                d[0] = make_uint2(v.x, v.y); d[1] = make_uint2(v.z, v.w);
            }
            __syncthreads();
#pragma unroll
            for (int kx = 0; kx < 3; kx++) {
                bf16x8v af[FM], bfr[FN];
#pragma unroll
                for (int fm = 0; fm < FM; fm++) {
                    int row = wm * 64 + fm * 16 + r + kx;
                    const uint2* p = (const uint2*)&As[row * 36 + g * 8];
                    union { uint2 u[2]; bf16x8v s; } uu; uu.u[0] = p[0]; uu.u[1] = p[1];
                    af[fm] = uu.s;
                }
#pragma unroll
                for (int fn = 0; fn < FN; fn++) {
                    const uint2* p = (const uint2*)&Bs[(kx * BN + wn * WN + fn * 16 + r) * 36 + g * 8];
                    union { uint2 u[2]; bf16x8v s; } uu; uu.u[0] = p[0]; uu.u[1] = p[1];
                    bfr[fn] = uu.s;
                }
#pragma unroll
                for (int fm = 0; fm < FM; fm++)
#pragma unroll
                    for (int fn = 0; fn < FN; fn++)
                        acc[fm][fn] = __builtin_amdgcn_mfma_f32_16x16x32_bf16(af[fm], bfr[fn], acc[fm][fn], 0, 0, 0);
            }
            __syncthreads();
        }
    }
#pragma unroll
    for (int fm = 0; fm < FM; fm++)
#pragma unroll
        for (int fn = 0; fn < FN; fn++)
#pragma unroll
            for (int reg = 0; reg < 4; reg++) {
                int xl = wm * 64 + fm * 16 + g * 4 + reg;
                int co = n0 + wn * WN + fn * 16 + r;
                float v = acc[fm][fn][reg];
                if constexpr (EPI == 1) v = 0.5f * v * (1.0f + erff(v * 0.70710678118654752f));
                outp[((size_t)mt * 128 + xl) * Cout + co] = tob(v);
            }
}

// ---------------- depthwise 3x3 on unpadded kv -> split k,v ----------------
__global__ __launch_bounds__(256) void k_dwconv(const bf16* __restrict__ kv,
                                                const float* __restrict__ wdw,
                                                bf16* __restrict__ kout,
                                                bf16* __restrict__ vout) {
    int gid = blockIdx.x * 256 + threadIdx.x;
    int c8 = gid % 48;
    int p = gid / 48;
    int b = p >> 14, pi = p & 16383, y = pi >> 7, x = pi & 127;
    int cbase = c8 * 8;
    float acc[8];
#pragma unroll
    for (int j = 0; j < 8; j++) acc[j] = 0.f;
    for (int ky = 0; ky < 3; ky++) {
        int yy = y + ky - 1;
        if (yy < 0 || yy > 127) continue;
        for (int kx = 0; kx < 3; kx++) {
            int xx = x + kx - 1;
            if (xx < 0 || xx > 127) continue;
            const bf16* src = kv + ((size_t)b * HW_ + yy * 128 + xx) * C2_ + cbase;
            uint4 vv = *(const uint4*)src;
            const bf16* pv = (const bf16*)&vv;
#pragma unroll
            for (int j = 0; j < 8; j++)
                acc[j] += fb(pv[j]) * wdw[(cbase + j) * 9 + ky * 3 + kx];
        }
    }
    union { bf16 h[8]; uint4 u; } ov;
#pragma unroll
    for (int j = 0; j < 8; j++) ov.h[j] = tob(acc[j]);
    bf16* dst = (c8 < 24) ? (kout + (size_t)p * C_ + cbase)
                          : (vout + (size_t)p * C_ + cbase - C_);
    *(uint4*)dst = ov.u;
}

// ---------------- deterministic per-(sel,b,c) sum-of-squares partials ----------------
__global__ void k_ssqpart(const bf16* __restrict__ q, const bf16* __restrict__ k,
                          float* __restrict__ ssq) {
    int c = threadIdx.x;  // 0..191
    int ch = blockIdx.x, b = blockIdx.y, sel = blockIdx.z;
    const bf16* src = (sel ? k : q) + ((size_t)b * HW_ + ch * 1024) * C_ + c;
    float s = 0.f;
    for (int i = 0; i < 1024; i++) { float v = fb(src[(size_t)i * C_]); s += v * v; }
    ssq[(((size_t)(sel * 2 + b)) * 16 + ch) * C_ + c] = s;
}

__global__ void k_inv(const float* __restrict__ ssq, float* __restrict__ inv) {
    int i = blockIdx.x * 256 + threadIdx.x;
    if (i >= 768) return;
    int sb = i / C_, c = i % C_;
    float s = 0.f;
    for (int ch = 0; ch < 16; ch++) s += ssq[((size_t)sb * 16 + ch) * C_ + c];
    inv[i] = 1.f / fmaxf(sqrtf(s), 1e-12f);
}

// ---------------- S partials: per (b,hd,chunk) 48x48 over 1024 positions ----------------
__global__ __launch_bounds__(256) void k_qk(const bf16* __restrict__ q,
                                            const bf16* __restrict__ k,
                                            float* __restrict__ Spart) {
    __shared__ float qs[64][49];
    __shared__ float ks[64][49];
    int t = threadIdx.x;
    int ch = blockIdx.x, hd = blockIdx.y, b = blockIdx.z;
    int i0 = (t >> 4) * 3, j0 = (t & 15) * 3;
    float acc[3][3];
#pragma unroll
    for (int a = 0; a < 3; a++)
#pragma unroll
        for (int c = 0; c < 3; c++) acc[a][c] = 0.f;

    for (int sub = 0; sub < 16; sub++) {
        size_t rbase = ((size_t)b * HW_ + ch * 1024 + sub * 64) * C_ + hd * 48;
        for (int i = t; i < 64 * 6; i += 256) {
            int row = i / 6, oc = i % 6;
            uint4 v = *(const uint4*)(q + rbase + (size_t)row * C_ + oc * 8);
            const bf16* pv = (const bf16*)&v;
#pragma unroll
            for (int j = 0; j < 8; j++) qs[row][oc * 8 + j] = fb(pv[j]);
            uint4 v2 = *(const uint4*)(k + rbase + (size_t)row * C_ + oc * 8);
            const bf16* pv2 = (const bf16*)&v2;
#pragma unroll
            for (int j = 0; j < 8; j++) ks[row][oc * 8 + j] = fb(pv2[j]);
        }
        __syncthreads();
        for (int p = 0; p < 64; p++) {
            float a0 = qs[p][i0], a1 = qs[p][i0 + 1], a2 = qs[p][i0 + 2];
            float b0 = ks[p][j0], b1 = ks[p][j0 + 1], b2 = ks[p][j0 + 2];
            acc[0][0] += a0 * b0; acc[0][1] += a0 * b1; acc[0][2] += a0 * b2;
            acc[1][0] += a1 * b0; acc[1][1] += a1 * b1; acc[1][2] += a1 * b2;
            acc[2][0] += a2 * b0; acc[2][1] += a2 * b1; acc[2][2] += a2 * b2;
        }
        __syncthreads();
    }
    float* dst = Spart + (((size_t)(b * 4 + hd)) * 16 + ch) * 2304;
#pragma unroll
    for (int a = 0; a < 3; a++)
#pragma unroll
        for (int c = 0; c < 3; c++) dst[(i0 + a) * 48 + (j0 + c)] = acc[a][c];
}

__global__ void k_softmax(const float* __restrict__ Spart, const float* __restrict__ invq,
                          const float* __restrict__ invk, const float* __restrict__ temp,
                          float* __restrict__ attn) {
    int t = threadIdx.x;
    if (t >= 48) return;
    int hd = blockIdx.x, b = blockIdx.y;
    const float* base = Spart + ((size_t)(b * 4 + hd)) * 16 * 2304;
    float qi = invq[b * C_ + hd * 48 + t];
    float tp = temp[hd];
    float row[48];
    float mx = -1e30f;
    for (int j = 0; j < 48; j++) {
        float s = 0.f;
        for (int ch = 0; ch < 16; ch++) s += base[ch * 2304 + t * 48 + j];
        s *= qi * invk[b * C_ + hd * 48 + j] * tp;
        row[j] = s;
        mx = fmaxf(mx, s);
    }
    float sum = 0.f;
    for (int j = 0; j < 48; j++) { row[j] = expf(row[j] - mx); sum += row[j]; }
    float is = 1.f / sum;
    for (int j = 0; j < 48; j++)
        attn[(((size_t)(b * 4 + hd)) * 48 + t) * 48 + j] = row[j] * is;
}

// ---------------- out = attn @ v  (per position, per head) ----------------
__global__ __launch_bounds__(256) void k_av(const float* __restrict__ attn,
                                            const bf16* __restrict__ v,
                                            bf16* __restrict__ out) {
    __shared__ float As[4 * 48 * 48];
    int t = threadIdx.x;
    int b = blockIdx.y;
    for (int i = t; i < 9216; i += 256) As[i] = attn[(size_t)b * 9216 + i];
    __syncthreads();
    int p = blockIdx.x * 64 + (t >> 2);
    int hd = t & 3;
    size_t row = (size_t)b * HW_ + p;
    const float* am = As + hd * 2304;
    float acc[48];
#pragma unroll
    for (int i = 0; i < 48; i++) acc[i] = 0.f;
#pragma unroll
    for (int jo = 0; jo < 6; jo++) {
        uint4 vv = *(const uint4*)(v + row * C_ + hd * 48 + jo * 8);
        const bf16* pv = (const bf16*)&vv;
#pragma unroll
        for (int jj = 0; jj < 8; jj++) {
            float vj = fb(pv[jj]);
            int j = jo * 8 + jj;
#pragma unroll
            for (int i = 0; i < 48; i++) acc[i] += am[i * 48 + j] * vj;
        }
    }
#pragma unroll
    for (int io = 0; io < 6; io++) {
        union { bf16 h[8]; uint4 u; } ov;
#pragma unroll
        for (int jj = 0; jj < 8; jj++) ov.h[jj] = tob(acc[io * 8 + jj]);
        *(uint4*)(out + row * C_ + hd * 48 + io * 8) = ov.u;
    }
}

// =====================================================================================
extern "C" void kernel_launch(void* const* d_in, const int* in_sizes, int n_in,
                              void* d_out, int out_size, void* d_ws, size_t ws_size,
                              hipStream_t stream) {
    const float* x     = (const float*)d_in[0];
    const float* illum = (const float*)d_in[1];
    const float* ln1w  = (const float*)d_in[2];
    const float* ln1b  = (const float*)d_in[3];
    const float* lnLw  = (const float*)d_in[4];
    const float* lnLb  = (const float*)d_in[5];
    const float* ln2w  = (const float*)d_in[6];
    const float* ln2b  = (const float*)d_in[7];
    const float* qw    = (const float*)d_in[8];
    const float* qdww  = (const float*)d_in[9];
    const float* kvw   = (const float*)d_in[10];
    const float* kvdww = (const float*)d_in[11];
    const float* temp  = (const float*)d_in[12];
    const float* projw = (const float*)d_in[13];
    const float* pinw  = (const float*)d_in[14];
    const float* dww   = (const float*)d_in[15];
    const float* poutw = (const float*)d_in[16];

    char* ws = (char*)d_ws;
    // ---- small region: weights + attention scratch [0, 7,375,872) ----
    bf16*  Wq1   = (bf16*)(ws + 0);         //   73,728
    bf16*  Wkv   = (bf16*)(ws + 73728);     //  147,456
    bf16*  Wqdw  = (bf16*)(ws + 221184);    //  663,552
    bf16*  Wproj = (bf16*)(ws + 884736);    //   73,728
    bf16*  Wpin  = (bf16*)(ws + 958464);    //  196,608
    bf16*  Wdw   = (bf16*)(ws + 1155072);   // 4,718,592
    bf16*  Wpout = (bf16*)(ws + 5873664);   //  196,608
    float* Spart = (float*)(ws + 6070272);  // 1,179,648
    float* attn  = (float*)(ws + 7249920);  //   73,728
    float* ssq   = (float*)(ws + 7323648);  //   49,152
    float* invv  = (float*)(ws + 7372800);  //    3,072
    // ---- activation arena: slots of u=12,582,912 bytes, lifetime-packed ----
    const size_t A0 = 7375872, u = 12582912;
    bf16* xn    = (bf16*)(ws + A0 + 0 * u);   // [LN1, kv-gemm]
    bf16* iln   = (bf16*)(ws + A0 + 1 * u);   // [LNL, q-1x1]
    bf16* qtmp  = (bf16*)(ws + A0 + 2 * u);   // [q-1x1, q-3x3]
    bf16* qb    = (bf16*)(ws + A0 + 1 * u);   // [q-3x3, qk]     (over iln)
    bf16* kvtmp = (bf16*)(ws + A0 + 2 * u);   // [kv-gemm, dwconv] 2 slots (over qtmp)
    bf16* kb    = (bf16*)(ws + A0 + 0 * u);   // [dwconv, qk]    (over xn)
    bf16* vb    = (bf16*)(ws + A0 + 4 * u);   // [dwconv, av]
    bf16* outa  = (bf16*)(ws + A0 + 2 * u);   // [av, proj]      (over kvtmp-lo)
    bf16* x2    = (bf16*)(ws + A0 + 0 * u);   // [proj, pout]    (over kb)
    bf16* xn2   = (bf16*)(ws + A0 + 3 * u);   // [LN2, pin]      (over kvtmp-hi)
    bf16* fbuf  = (bf16*)(ws + A0 + 4 * u);   // [pin, dw3x3]  33,554,432 (over vb)
    bf16* gbuf  = (bf16*)(ws + A0 + 1 * u);   // [dw3x3, pout] 33,554,432 (over qb/outa/xn2)
    // total = A0 + 4u + 33,554,432 = 91,261,952 bytes (~87 MB)

    // 0) weight repacks (bf16, zero-padded channels)
    k_repack1<<<(192 * 192 + 255) / 256, 256, 0, stream>>>(qw, Wq1, 192, 192, 192, 192);
    k_repack1<<<(384 * 192 + 255) / 256, 256, 0, stream>>>(kvw, Wkv, 384, 192, 384, 192);
    k_repack3<<<(9 * 192 * 192 + 255) / 256, 256, 0, stream>>>(qdww, Wqdw, 192, 192, 192, 192);
    k_repack1<<<(192 * 192 + 255) / 256, 256, 0, stream>>>(projw, Wproj, 192, 192, 192, 192);
    k_repack1<<<(512 * 192 + 255) / 256, 256, 0, stream>>>(pinw, Wpin, 510, 192, 512, 192);
    k_repack3<<<(9 * 512 * 512 + 255) / 256, 256, 0, stream>>>(dww, Wdw, 510, 510, 512, 512);
    k_repack1<<<(192 * 512 + 255) / 256, 256, 0, stream>>>(poutw, Wpout, 192, 510, 192, 512);

    // 1) LayerNorms
    k_ln_nchw<<<512, 256, 0, stream>>>(x, ln1w, ln1b, xn);
    k_ln_nchw<<<512, 256, 0, stream>>>(illum, lnLw, lnLb, iln);

    // 2) q = 1x1(iln) ; then full 3x3 -> qb
    k_gemm1x1<96, 1><<<dim3(256, 2), 256, 0, stream>>>(iln, Wq1, 192, 192, qtmp, nullptr);
    k_gemm3x3<96, 0><<<dim3(256, 2), 256, 0, stream>>>(qtmp, Wqdw, 192, 192, qb);

    // 3) kv = 1x1(xn) ; depthwise 3x3 -> kb, vb
    k_gemm1x1<128, 1><<<dim3(256, 3), 256, 0, stream>>>(xn, Wkv, 192, 384, kvtmp, nullptr);
    k_dwconv<<<(B_ * HW_ * 48) / 256, 256, 0, stream>>>(kvtmp, kvdww, kb, vb);

    // 4) attention
    k_ssqpart<<<dim3(16, 2, 2), 192, 0, stream>>>(qb, kb, ssq);
    k_inv<<<3, 256, 0, stream>>>(ssq, invv);
    k_qk<<<dim3(16, 4, 2), 256, 0, stream>>>(qb, kb, Spart);
    k_softmax<<<dim3(4, 2), 64, 0, stream>>>(Spart, invv, invv + 384, temp, attn);
    k_av<<<dim3(256, 2), 256, 0, stream>>>(attn, vb, outa);

    // 5) x2 = x + proj(out)   (bf16 residual stream)
    k_gemm1x1<96, 2><<<dim3(256, 2), 256, 0, stream>>>(outa, Wproj, 192, 192, x2, x);

    // 6) FFN
    k_ln_pc<<<512, 256, 0, stream>>>(x2, ln2w, ln2b, xn2);
    k_gemm1x1<128, 1><<<dim3(256, 4), 256, 0, stream>>>(xn2, Wpin, 192, 512, fbuf, nullptr);
    k_gemm3x3<128, 1><<<dim3(256, 4), 256, 0, stream>>>(fbuf, Wdw, 512, 512, gbuf);
    k_gemm1x1<96, 3><<<dim3(256, 2), 256, 0, stream>>>(gbuf, Wpout, 512, 192, d_out, x2);
}

// Round 3
// 681.081 us; speedup vs baseline: 1.2615x; 1.2615x over previous
//
#include <hip/hip_runtime.h>
#include <hip/hip_bf16.h>

typedef __hip_bfloat16 bf16;
typedef __attribute__((ext_vector_type(8))) short bf16x8v;
typedef __attribute__((ext_vector_type(4))) float f32x4;

namespace {
constexpr int B_  = 2;
constexpr int C_  = 192;
constexpr int HW_ = 128 * 128;   // 16384
constexpr int C2_ = 384;
}

static __device__ __forceinline__ float fb(bf16 v) { return __bfloat162float(v); }
static __device__ __forceinline__ bf16 tob(float v) { return __float2bfloat16(v); }

typedef __attribute__((address_space(1))) const char GChar;
typedef __attribute__((address_space(3))) char LChar;
// async global->LDS, 16B per lane; LDS dest = wave-uniform base + lane*16
static __device__ __forceinline__ void gl16(const void* g, void* l) {
    __builtin_amdgcn_global_load_lds((GChar*)g, (LChar*)l, 16, 0, 0);
}
// swizzled LDS fragment read: 128B rows, 16B slots, slot ^= row&7
static __device__ __forceinline__ bf16x8v lread(const bf16* base, int row, int slot) {
    const char* p = (const char*)base + (size_t)row * 128 + ((size_t)((slot ^ (row & 7))) << 4);
    return *(const bf16x8v*)p;
}

// ---------------- weight repack: fp32 -> bf16 (optionally zero-padded) ----------------
__global__ void k_repack1(const float* __restrict__ W, bf16* __restrict__ Wr,
                          int N, int K, int Npad, int Kpad) {
    int i = blockIdx.x * 256 + threadIdx.x;
    if (i >= Npad * Kpad) return;
    int n = i / Kpad, k = i % Kpad;
    float v = (n < N && k < K) ? W[n * K + k] : 0.f;
    Wr[i] = tob(v);
}

// W[(n*K+k)*9 + q] -> Wr[(q*Npad + n)*Kpad + k]
__global__ void k_repack3(const float* __restrict__ W, bf16* __restrict__ Wr,
                          int N, int K, int Npad, int Kpad) {
    int i = blockIdx.x * 256 + threadIdx.x;
    if (i >= 9 * Npad * Kpad) return;
    int q = i / (Npad * Kpad);
    int rem = i % (Npad * Kpad);
    int n = rem / Kpad, k = rem % Kpad;
    float v = (n < N && k < K) ? W[(n * K + k) * 9 + q] : 0.f;
    Wr[i] = tob(v);
}

// ---------------- LayerNorm: NCHW fp32 -> [p][c] bf16 ----------------
__global__ __launch_bounds__(256) void k_ln_nchw(const float* __restrict__ X,
                                                 const float* __restrict__ w,
                                                 const float* __restrict__ bb,
                                                 bf16* __restrict__ out) {
    __shared__ float lds[64][C_ + 1];
    int t = threadIdx.x;
    int p0 = blockIdx.x * 64;
    int b = p0 / HW_, pi0 = p0 % HW_;
    for (int i = t; i < 64 * C_; i += 256) {
        int c = i >> 6, pp = i & 63;
        lds[pp][c] = X[((size_t)(b * C_ + c)) * HW_ + pi0 + pp];
    }
    __syncthreads();
    int pp = t >> 2, qq = t & 3;
    float s = 0.f, s2 = 0.f;
    for (int c = qq * 48; c < qq * 48 + 48; c++) { float v = lds[pp][c]; s += v; s2 += v * v; }
    s  += __shfl_xor(s, 1);  s  += __shfl_xor(s, 2);
    s2 += __shfl_xor(s2, 1); s2 += __shfl_xor(s2, 2);
    float mu = s / C_;
    float rstd = rsqrtf(s2 / C_ - mu * mu + 1e-5f);
    size_t ob = ((size_t)(p0 + pp)) * C_;
    for (int c = qq * 48; c < qq * 48 + 48; c++)
        out[ob + c] = tob((lds[pp][c] - mu) * rstd * w[c] + bb[c]);
}

// LayerNorm from [p][c] bf16 -> [p][c] bf16
__global__ __launch_bounds__(256) void k_ln_pc(const bf16* __restrict__ X2,
                                               const float* __restrict__ w,
                                               const float* __restrict__ bb,
                                               bf16* __restrict__ out) {
    int t = threadIdx.x;
    int p = blockIdx.x * 64 + (t >> 2), qq = t & 3;
    const bf16* row = X2 + (size_t)p * C_;
    float s = 0.f, s2 = 0.f;
    for (int c = qq * 48; c < qq * 48 + 48; c++) { float v = fb(row[c]); s += v; s2 += v * v; }
    s  += __shfl_xor(s, 1);  s  += __shfl_xor(s, 2);
    s2 += __shfl_xor(s2, 1); s2 += __shfl_xor(s2, 2);
    float mu = s / C_;
    float rstd = rsqrtf(s2 / C_ - mu * mu + 1e-5f);
    bf16* orow = out + (size_t)p * C_;
    for (int c = qq * 48; c < qq * 48 + 48; c++)
        orow[c] = tob((fb(row[c]) - mu) * rstd * w[c] + bb[c]);
}

// ---------------- 1x1 conv GEMM (global_load_lds + swizzle), BK=64 ----------------
// EPI: 1 = plain bf16 [p][Cout]
//      2 = +resid(NCHW f32)  -> bf16 [p][C_]
//      3 = +resid(bf16 [p][C_]) -> f32 NCHW
template <int BN, int EPI>
__global__ __launch_bounds__(256) void k_gemm1x1(const bf16* __restrict__ A,
                                                 const bf16* __restrict__ Wr,
                                                 const int K, const int Cout,
                                                 void* __restrict__ outp,
                                                 const void* __restrict__ resid) {
    constexpr int WN = BN / 2, FN = WN / 16, BIT = BN / 32;
    __shared__ __align__(16) bf16 As[128 * 64];
    __shared__ __align__(16) bf16 Bs[BN * 64];
    const int t = threadIdx.x;
    const int mt = blockIdx.x;
    const int n0 = blockIdx.y * BN;
    const int w = t >> 6, lane = t & 63;
    const int wm = w >> 1, wn = w & 1;
    const int g = lane >> 4, r = lane & 15;
    const int ldw = t - lane;  // w*64

    f32x4 acc[4][FN];
#pragma unroll
    for (int i = 0; i < 4; i++)
#pragma unroll
        for (int j = 0; j < FN; j++) acc[i][j] = {0.f, 0.f, 0.f, 0.f};

    const bf16* Abase = A + (size_t)mt * 128 * K;

    for (int c0 = 0; c0 < K; c0 += 64) {
#pragma unroll
        for (int it = 0; it < 4; it++) {
            int idx = it * 256 + t;
            int row = idx >> 3, sl = idx & 7;
            const char* gp = (const char*)(Abase + (size_t)row * K + c0) + ((sl ^ (row & 7)) << 4);
            gl16(gp, (char*)As + (size_t)(it * 256 + ldw) * 16);
        }
#pragma unroll
        for (int it = 0; it < BIT; it++) {
            int idx = it * 256 + t;
            int row = idx >> 3, sl = idx & 7;
            const char* gp = (const char*)(Wr + (size_t)(n0 + row) * K + c0) + ((sl ^ (row & 7)) << 4);
            gl16(gp, (char*)Bs + (size_t)(it * 256 + ldw) * 16);
        }
        __syncthreads();
#pragma unroll
        for (int ks = 0; ks < 2; ks++) {
            bf16x8v af[4], bv[FN];
#pragma unroll
            for (int fm = 0; fm < 4; fm++)
                af[fm] = lread(As, wm * 64 + fm * 16 + r, ks * 4 + g);
#pragma unroll
            for (int fn = 0; fn < FN; fn++)
                bv[fn] = lread(Bs, wn * WN + fn * 16 + r, ks * 4 + g);
#pragma unroll
            for (int fm = 0; fm < 4; fm++)
#pragma unroll
                for (int fn = 0; fn < FN; fn++)
                    acc[fm][fn] = __builtin_amdgcn_mfma_f32_16x16x32_bf16(af[fm], bv[fn], acc[fm][fn], 0, 0, 0);
        }
        __syncthreads();
    }

    const int b = mt >> 7, y = mt & 127;
#pragma unroll
    for (int fm = 0; fm < 4; fm++)
#pragma unroll
        for (int fn = 0; fn < FN; fn++)
#pragma unroll
            for (int reg = 0; reg < 4; reg++) {
                int xl = wm * 64 + fm * 16 + g * 4 + reg;
                int co = n0 + wn * WN + fn * 16 + r;
                float v = acc[fm][fn][reg];
                if constexpr (EPI == 1) {
                    ((bf16*)outp)[((size_t)mt * 128 + xl) * Cout + co] = tob(v);
                } else if constexpr (EPI == 2) {
                    v += ((const float*)resid)[((size_t)(b * C_ + co)) * HW_ + y * 128 + xl];
                    ((bf16*)outp)[((size_t)mt * 128 + xl) * C_ + co] = tob(v);
                } else {
                    v += fb(((const bf16*)resid)[((size_t)mt * 128 + xl) * C_ + co]);
                    ((float*)outp)[((size_t)(b * C_ + co)) * HW_ + y * 128 + xl] = v;
                }
            }
}

// ---------------- 3x3 full conv implicit GEMM (global_load_lds + swizzle + zero page) --
// A tile: 160 rows x 64ch (rows 1..128 = x 0..127; rows 0,129+ = zero page)
// B tile: BN rows x 64ch, staged per kx. EPI: 0 = plain bf16, 1 = GELU bf16
template <int BN, int EPI>
__global__ __launch_bounds__(256) void k_gemm3x3(const bf16* __restrict__ A,
                                                 const bf16* __restrict__ Wr,
                                                 const int Cin, const int Cout,
                                                 bf16* __restrict__ outp,
                                                 const char* __restrict__ zpage) {
    constexpr int WN = BN / 2, FN = WN / 16, BIT = BN / 32;
    __shared__ __align__(16) bf16 As[160 * 64];
    __shared__ __align__(16) bf16 Bs[BN * 64];
    const int t = threadIdx.x;
    const int mt = blockIdx.x;
    const int n0 = blockIdx.y * BN;
    const int b = mt >> 7, y = mt & 127;
    const int w = t >> 6, lane = t & 63;
    const int wm = w >> 1, wn = w & 1;
    const int g = lane >> 4, r = lane & 15;
    const int ldw = t - lane;

    f32x4 acc[4][FN];
#pragma unroll
    for (int i = 0; i < 4; i++)
#pragma unroll
        for (int j = 0; j < FN; j++) acc[i][j] = {0.f, 0.f, 0.f, 0.f};

    for (int ky = 0; ky < 3; ky++) {
        const int yy = y + ky - 1;
        if (yy < 0 || yy > 127) continue;   // block-uniform
        const bf16* Ab = A + ((size_t)b * HW_ + (size_t)yy * 128) * Cin;
        for (int c0 = 0; c0 < Cin; c0 += 64) {
            for (int kx = 0; kx < 3; kx++) {
                if (kx == 0) {
#pragma unroll
                    for (int it = 0; it < 5; it++) {
                        int idx = it * 256 + t;
                        int row = idx >> 3, sl = idx & 7;
                        int so = (sl ^ (row & 7)) << 4;
                        const char* gp = (row >= 1 && row <= 128)
                            ? (const char*)(Ab + (size_t)(row - 1) * Cin + c0) + so
                            : zpage + so;
                        gl16(gp, (char*)As + (size_t)(it * 256 + ldw) * 16);
                    }
                }
                const bf16* Wb = Wr + (size_t)(ky * 3 + kx) * Cout * Cin;
#pragma unroll
                for (int it = 0; it < BIT; it++) {
                    int idx = it * 256 + t;
                    int row = idx >> 3, sl = idx & 7;
                    const char* gp = (const char*)(Wb + (size_t)(n0 + row) * Cin + c0) + ((sl ^ (row & 7)) << 4);
                    gl16(gp, (char*)Bs + (size_t)(it * 256 + ldw) * 16);
                }
                __syncthreads();
#pragma unroll
                for (int ks = 0; ks < 2; ks++) {
                    bf16x8v af[4], bv[FN];
#pragma unroll
                    for (int fm = 0; fm < 4; fm++)
                        af[fm] = lread(As, wm * 64 + fm * 16 + r + kx, ks * 4 + g);
#pragma unroll
                    for (int fn = 0; fn < FN; fn++)
                        bv[fn] = lread(Bs, wn * WN + fn * 16 + r, ks * 4 + g);
#pragma unroll
                    for (int fm = 0; fm < 4; fm++)
#pragma unroll
                        for (int fn = 0; fn < FN; fn++)
                            acc[fm][fn] = __builtin_amdgcn_mfma_f32_16x16x32_bf16(af[fm], bv[fn], acc[fm][fn], 0, 0, 0);
                }
                __syncthreads();
            }
        }
    }
#pragma unroll
    for (int fm = 0; fm < 4; fm++)
#pragma unroll
        for (int fn = 0; fn < FN; fn++)
#pragma unroll
            for (int reg = 0; reg < 4; reg++) {
                int xl = wm * 64 + fm * 16 + g * 4 + reg;
                int co = n0 + wn * WN + fn * 16 + r;
                float v = acc[fm][fn][reg];
                if constexpr (EPI == 1) v = 0.5f * v * (1.0f + erff(v * 0.70710678118654752f));
                outp[((size_t)mt * 128 + xl) * Cout + co] = tob(v);
            }
}

// ---------------- depthwise 3x3 on unpadded kv -> split k,v ----------------
__global__ __launch_bounds__(256) void k_dwconv(const bf16* __restrict__ kv,
                                                const float* __restrict__ wdw,
                                                bf16* __restrict__ kout,
                                                bf16* __restrict__ vout) {
    int gid = blockIdx.x * 256 + threadIdx.x;
    int c8 = gid % 48;
    int p = gid / 48;
    int b = p >> 14, pi = p & 16383, y = pi >> 7, x = pi & 127;
    int cbase = c8 * 8;
    float acc[8];
#pragma unroll
    for (int j = 0; j < 8; j++) acc[j] = 0.f;
    for (int ky = 0; ky < 3; ky++) {
        int yy = y + ky - 1;
        if (yy < 0 || yy > 127) continue;
        for (int kx = 0; kx < 3; kx++) {
            int xx = x + kx - 1;
            if (xx < 0 || xx > 127) continue;
            const bf16* src = kv + ((size_t)b * HW_ + yy * 128 + xx) * C2_ + cbase;
            uint4 vv = *(const uint4*)src;
            const bf16* pv = (const bf16*)&vv;
#pragma unroll
            for (int j = 0; j < 8; j++)
                acc[j] += fb(pv[j]) * wdw[(cbase + j) * 9 + ky * 3 + kx];
        }
    }
    union { bf16 h[8]; uint4 u; } ov;
#pragma unroll
    for (int j = 0; j < 8; j++) ov.h[j] = tob(acc[j]);
    bf16* dst = (c8 < 24) ? (kout + (size_t)p * C_ + cbase)
                          : (vout + (size_t)p * C_ + cbase - C_);
    *(uint4*)dst = ov.u;
}

// ---------------- deterministic per-(sel,b,c) sum-of-squares partials ----------------
__global__ void k_ssqpart(const bf16* __restrict__ q, const bf16* __restrict__ k,
                          float* __restrict__ ssq) {
    int c = threadIdx.x;  // 0..191
    int ch = blockIdx.x, b = blockIdx.y, sel = blockIdx.z;
    const bf16* src = (sel ? k : q) + ((size_t)b * HW_ + ch * 1024) * C_ + c;
    float s = 0.f;
    for (int i = 0; i < 1024; i++) { float v = fb(src[(size_t)i * C_]); s += v * v; }
    ssq[(((size_t)(sel * 2 + b)) * 16 + ch) * C_ + c] = s;
}

__global__ void k_inv(const float* __restrict__ ssq, float* __restrict__ inv) {
    int i = blockIdx.x * 256 + threadIdx.x;
    if (i >= 768) return;
    int sb = i / C_, c = i % C_;
    float s = 0.f;
    for (int ch = 0; ch < 16; ch++) s += ssq[((size_t)sb * 16 + ch) * C_ + c];
    inv[i] = 1.f / fmaxf(sqrtf(s), 1e-12f);
}

// ---------------- S partials: per (b,hd,chunk) 48x48 over 1024 positions ----------------
__global__ __launch_bounds__(256) void k_qk(const bf16* __restrict__ q,
                                            const bf16* __restrict__ k,
                                            float* __restrict__ Spart) {
    __shared__ float qs[64][49];
    __shared__ float ks[64][49];
    int t = threadIdx.x;
    int ch = blockIdx.x, hd = blockIdx.y, b = blockIdx.z;
    int i0 = (t >> 4) * 3, j0 = (t & 15) * 3;
    float acc[3][3];
#pragma unroll
    for (int a = 0; a < 3; a++)
#pragma unroll
        for (int c = 0; c < 3; c++) acc[a][c] = 0.f;

    for (int sub = 0; sub < 16; sub++) {
        size_t rbase = ((size_t)b * HW_ + ch * 1024 + sub * 64) * C_ + hd * 48;
        for (int i = t; i < 64 * 6; i += 256) {
            int row = i / 6, oc = i % 6;
            uint4 v = *(const uint4*)(q + rbase + (size_t)row * C_ + oc * 8);
            const bf16* pv = (const bf16*)&v;
#pragma unroll
            for (int j = 0; j < 8; j++) qs[row][oc * 8 + j] = fb(pv[j]);
            uint4 v2 = *(const uint4*)(k + rbase + (size_t)row * C_ + oc * 8);
            const bf16* pv2 = (const bf16*)&v2;
#pragma unroll
            for (int j = 0; j < 8; j++) ks[row][oc * 8 + j] = fb(pv2[j]);
        }
        __syncthreads();
        for (int p = 0; p < 64; p++) {
            float a0 = qs[p][i0], a1 = qs[p][i0 + 1], a2 = qs[p][i0 + 2];
            float b0 = ks[p][j0], b1 = ks[p][j0 + 1], b2 = ks[p][j0 + 2];
            acc[0][0] += a0 * b0; acc[0][1] += a0 * b1; acc[0][2] += a0 * b2;
            acc[1][0] += a1 * b0; acc[1][1] += a1 * b1; acc[1][2] += a1 * b2;
            acc[2][0] += a2 * b0; acc[2][1] += a2 * b1; acc[2][2] += a2 * b2;
        }
        __syncthreads();
    }
    float* dst = Spart + (((size_t)(b * 4 + hd)) * 16 + ch) * 2304;
#pragma unroll
    for (int a = 0; a < 3; a++)
#pragma unroll
        for (int c = 0; c < 3; c++) dst[(i0 + a) * 48 + (j0 + c)] = acc[a][c];
}

__global__ void k_softmax(const float* __restrict__ Spart, const float* __restrict__ invq,
                          const float* __restrict__ invk, const float* __restrict__ temp,
                          float* __restrict__ attn) {
    int t = threadIdx.x;
    if (t >= 48) return;
    int hd = blockIdx.x, b = blockIdx.y;
    const float* base = Spart + ((size_t)(b * 4 + hd)) * 16 * 2304;
    float qi = invq[b * C_ + hd * 48 + t];
    float tp = temp[hd];
    float row[48];
    float mx = -1e30f;
    for (int j = 0; j < 48; j++) {
        float s = 0.f;
        for (int ch = 0; ch < 16; ch++) s += base[ch * 2304 + t * 48 + j];
        s *= qi * invk[b * C_ + hd * 48 + j] * tp;
        row[j] = s;
        mx = fmaxf(mx, s);
    }
    float sum = 0.f;
    for (int j = 0; j < 48; j++) { row[j] = expf(row[j] - mx); sum += row[j]; }
    float is = 1.f / sum;
    for (int j = 0; j < 48; j++)
        attn[(((size_t)(b * 4 + hd)) * 48 + t) * 48 + j] = row[j] * is;
}

// ---------------- out = attn @ v  (per position, per head) ----------------
__global__ __launch_bounds__(256) void k_av(const float* __restrict__ attn,
                                            const bf16* __restrict__ v,
                                            bf16* __restrict__ out) {
    __shared__ float As[4 * 48 * 48];
    int t = threadIdx.x;
    int b = blockIdx.y;
    for (int i = t; i < 9216; i += 256) As[i] = attn[(size_t)b * 9216 + i];
    __syncthreads();
    int p = blockIdx.x * 64 + (t >> 2);
    int hd = t & 3;
    size_t row = (size_t)b * HW_ + p;
    const float* am = As + hd * 2304;
    float acc[48];
#pragma unroll
    for (int i = 0; i < 48; i++) acc[i] = 0.f;
#pragma unroll
    for (int jo = 0; jo < 6; jo++) {
        uint4 vv = *(const uint4*)(v + row * C_ + hd * 48 + jo * 8);
        const bf16* pv = (const bf16*)&vv;
#pragma unroll
        for (int jj = 0; jj < 8; jj++) {
            float vj = fb(pv[jj]);
            int j = jo * 8 + jj;
#pragma unroll
            for (int i = 0; i < 48; i++) acc[i] += am[i * 48 + j] * vj;
        }
    }
#pragma unroll
    for (int io = 0; io < 6; io++) {
        union { bf16 h[8]; uint4 u; } ov;
#pragma unroll
        for (int jj = 0; jj < 8; jj++) ov.h[jj] = tob(acc[io * 8 + jj]);
        *(uint4*)(out + row * C_ + hd * 48 + io * 8) = ov.u;
    }
}

// =====================================================================================
extern "C" void kernel_launch(void* const* d_in, const int* in_sizes, int n_in,
                              void* d_out, int out_size, void* d_ws, size_t ws_size,
                              hipStream_t stream) {
    const float* x     = (const float*)d_in[0];
    const float* illum = (const float*)d_in[1];
    const float* ln1w  = (const float*)d_in[2];
    const float* ln1b  = (const float*)d_in[3];
    const float* lnLw  = (const float*)d_in[4];
    const float* lnLb  = (const float*)d_in[5];
    const float* ln2w  = (const float*)d_in[6];
    const float* ln2b  = (const float*)d_in[7];
    const float* qw    = (const float*)d_in[8];
    const float* qdww  = (const float*)d_in[9];
    const float* kvw   = (const float*)d_in[10];
    const float* kvdww = (const float*)d_in[11];
    const float* temp  = (const float*)d_in[12];
    const float* projw = (const float*)d_in[13];
    const float* pinw  = (const float*)d_in[14];
    const float* dww   = (const float*)d_in[15];
    const float* poutw = (const float*)d_in[16];

    char* ws = (char*)d_ws;
    // ---- small region: weights + attention scratch ----
    bf16*  Wq1   = (bf16*)(ws + 0);         //   73,728
    bf16*  Wkv   = (bf16*)(ws + 73728);     //  147,456
    bf16*  Wqdw  = (bf16*)(ws + 221184);    //  663,552
    bf16*  Wproj = (bf16*)(ws + 884736);    //   73,728
    bf16*  Wpin  = (bf16*)(ws + 958464);    //  196,608
    bf16*  Wdw   = (bf16*)(ws + 1155072);   // 4,718,592
    bf16*  Wpout = (bf16*)(ws + 5873664);   //  196,608
    float* Spart = (float*)(ws + 6070272);  // 1,179,648
    float* attn  = (float*)(ws + 7249920);  //   73,728
    float* ssq   = (float*)(ws + 7323648);  //   49,152
    float* invv  = (float*)(ws + 7372800);  //    3,072
    char*  zpage = (char*)(ws + 7375872);   //    4,096 zero page for border lanes
    // ---- activation arena: slots of u=12,582,912 bytes, lifetime-packed ----
    const size_t A0 = 7379968, u = 12582912;
    bf16* xn    = (bf16*)(ws + A0 + 0 * u);   // [LN1, kv-gemm]
    bf16* iln   = (bf16*)(ws + A0 + 1 * u);   // [LNL, q-1x1]
    bf16* qtmp  = (bf16*)(ws + A0 + 2 * u);   // [q-1x1, q-3x3]
    bf16* qb    = (bf16*)(ws + A0 + 1 * u);   // [q-3x3, qk]     (over iln)
    bf16* kvtmp = (bf16*)(ws + A0 + 2 * u);   // [kv-gemm, dwconv] 2 slots (over qtmp)
    bf16* kb    = (bf16*)(ws + A0 + 0 * u);   // [dwconv, qk]    (over xn)
    bf16* vb    = (bf16*)(ws + A0 + 4 * u);   // [dwconv, av]
    bf16* outa  = (bf16*)(ws + A0 + 2 * u);   // [av, proj]      (over kvtmp-lo)
    bf16* x2    = (bf16*)(ws + A0 + 0 * u);   // [proj, pout]    (over kb)
    bf16* xn2   = (bf16*)(ws + A0 + 3 * u);   // [LN2, pin]      (over kvtmp-hi)
    bf16* fbuf  = (bf16*)(ws + A0 + 4 * u);   // [pin, dw3x3]  33,554,432 (over vb)
    bf16* gbuf  = (bf16*)(ws + A0 + 1 * u);   // [dw3x3, pout] 33,554,432 (slots 1-3)
    // total = A0 + 4u + 33,554,432 = 91,266,048 bytes (~87 MB)

    hipMemsetAsync(zpage, 0, 4096, stream);

    // 0) weight repacks (bf16, zero-padded channels)
    k_repack1<<<(192 * 192 + 255) / 256, 256, 0, stream>>>(qw, Wq1, 192, 192, 192, 192);
    k_repack1<<<(384 * 192 + 255) / 256, 256, 0, stream>>>(kvw, Wkv, 384, 192, 384, 192);
    k_repack3<<<(9 * 192 * 192 + 255) / 256, 256, 0, stream>>>(qdww, Wqdw, 192, 192, 192, 192);
    k_repack1<<<(192 * 192 + 255) / 256, 256, 0, stream>>>(projw, Wproj, 192, 192, 192, 192);
    k_repack1<<<(512 * 192 + 255) / 256, 256, 0, stream>>>(pinw, Wpin, 510, 192, 512, 192);
    k_repack3<<<(9 * 512 * 512 + 255) / 256, 256, 0, stream>>>(dww, Wdw, 510, 510, 512, 512);
    k_repack1<<<(192 * 512 + 255) / 256, 256, 0, stream>>>(poutw, Wpout, 192, 510, 192, 512);

    // 1) LayerNorms
    k_ln_nchw<<<512, 256, 0, stream>>>(x, ln1w, ln1b, xn);
    k_ln_nchw<<<512, 256, 0, stream>>>(illum, lnLw, lnLb, iln);

    // 2) q = 1x1(iln) ; then full 3x3 -> qb
    k_gemm1x1<96, 1><<<dim3(256, 2), 256, 0, stream>>>(iln, Wq1, 192, 192, qtmp, nullptr);
    k_gemm3x3<96, 0><<<dim3(256, 2), 256, 0, stream>>>(qtmp, Wqdw, 192, 192, qb, zpage);

    // 3) kv = 1x1(xn) ; depthwise 3x3 -> kb, vb
    k_gemm1x1<128, 1><<<dim3(256, 3), 256, 0, stream>>>(xn, Wkv, 192, 384, kvtmp, nullptr);
    k_dwconv<<<(B_ * HW_ * 48) / 256, 256, 0, stream>>>(kvtmp, kvdww, kb, vb);

    // 4) attention
    k_ssqpart<<<dim3(16, 2, 2), 192, 0, stream>>>(qb, kb, ssq);
    k_inv<<<3, 256, 0, stream>>>(ssq, invv);
    k_qk<<<dim3(16, 4, 2), 256, 0, stream>>>(qb, kb, Spart);
    k_softmax<<<dim3(4, 2), 64, 0, stream>>>(Spart, invv, invv + 384, temp, attn);
    k_av<<<dim3(256, 2), 256, 0, stream>>>(attn, vb, outa);

    // 5) x2 = x + proj(out)   (bf16 residual stream)
    k_gemm1x1<96, 2><<<dim3(256, 2), 256, 0, stream>>>(outa, Wproj, 192, 192, x2, x);

    // 6) FFN
    k_ln_pc<<<512, 256, 0, stream>>>(x2, ln2w, ln2b, xn2);
    k_gemm1x1<128, 1><<<dim3(256, 4), 256, 0, stream>>>(xn2, Wpin, 192, 512, fbuf, nullptr);
    k_gemm3x3<128, 1><<<dim3(256, 4), 256, 0, stream>>>(fbuf, Wdw, 512, 512, gbuf, zpage);
    k_gemm1x1<96, 3><<<dim3(256, 2), 256, 0, stream>>>(gbuf, Wpout, 512, 192, d_out, x2);
}

// Round 4
// 516.164 us; speedup vs baseline: 1.6645x; 1.3195x over previous
//
#include <hip/hip_runtime.h>
#include <hip/hip_bf16.h>

typedef __hip_bfloat16 bf16;
typedef __attribute__((ext_vector_type(8))) short bf16x8v;
typedef __attribute__((ext_vector_type(4))) float f32x4;

namespace {
constexpr int B_  = 2;
constexpr int C_  = 192;
constexpr int HW_ = 128 * 128;   // 16384
constexpr int C2_ = 384;
}

static __device__ __forceinline__ float fb(bf16 v) { return __bfloat162float(v); }
static __device__ __forceinline__ bf16 tob(float v) { return __float2bfloat16(v); }

typedef __attribute__((address_space(1))) const char GChar;
typedef __attribute__((address_space(3))) char LChar;
// async global->LDS, 16B per lane; LDS dest = wave-uniform base + lane*16
static __device__ __forceinline__ void gl16(const void* g, void* l) {
    __builtin_amdgcn_global_load_lds((GChar*)g, (LChar*)l, 16, 0, 0);
}
// swizzled LDS fragment read: 128B rows, 16B slots, slot ^= row&7
static __device__ __forceinline__ bf16x8v lread(const bf16* base, int row, int slot) {
    const char* p = (const char*)base + (size_t)row * 128 + ((size_t)((slot ^ (row & 7))) << 4);
    return *(const bf16x8v*)p;
}

// ---------------- weight repack: fp32 -> bf16 (optionally zero-padded) ----------------
__global__ void k_repack1(const float* __restrict__ W, bf16* __restrict__ Wr,
                          int N, int K, int Npad, int Kpad) {
    int i = blockIdx.x * 256 + threadIdx.x;
    if (i >= Npad * Kpad) return;
    int n = i / Kpad, k = i % Kpad;
    float v = (n < N && k < K) ? W[n * K + k] : 0.f;
    Wr[i] = tob(v);
}

// W[(n*K+k)*9 + q] -> Wr[(q*Npad + n)*Kpad + k]
__global__ void k_repack3(const float* __restrict__ W, bf16* __restrict__ Wr,
                          int N, int K, int Npad, int Kpad) {
    int i = blockIdx.x * 256 + threadIdx.x;
    if (i >= 9 * Npad * Kpad) return;
    int q = i / (Npad * Kpad);
    int rem = i % (Npad * Kpad);
    int n = rem / Kpad, k = rem % Kpad;
    float v = (n < N && k < K) ? W[(n * K + k) * 9 + q] : 0.f;
    Wr[i] = tob(v);
}

// ---------------- LayerNorm: NCHW fp32 -> [p][c] bf16 ----------------
__global__ __launch_bounds__(256) void k_ln_nchw(const float* __restrict__ X,
                                                 const float* __restrict__ w,
                                                 const float* __restrict__ bb,
                                                 bf16* __restrict__ out) {
    __shared__ float lds[64][C_ + 1];
    int t = threadIdx.x;
    int p0 = blockIdx.x * 64;
    int b = p0 / HW_, pi0 = p0 % HW_;
    for (int i = t; i < 64 * C_; i += 256) {
        int c = i >> 6, pp = i & 63;
        lds[pp][c] = X[((size_t)(b * C_ + c)) * HW_ + pi0 + pp];
    }
    __syncthreads();
    int pp = t >> 2, qq = t & 3;
    float s = 0.f, s2 = 0.f;
    for (int c = qq * 48; c < qq * 48 + 48; c++) { float v = lds[pp][c]; s += v; s2 += v * v; }
    s  += __shfl_xor(s, 1);  s  += __shfl_xor(s, 2);
    s2 += __shfl_xor(s2, 1); s2 += __shfl_xor(s2, 2);
    float mu = s / C_;
    float rstd = rsqrtf(s2 / C_ - mu * mu + 1e-5f);
    size_t ob = ((size_t)(p0 + pp)) * C_;
    for (int c = qq * 48; c < qq * 48 + 48; c++)
        out[ob + c] = tob((lds[pp][c] - mu) * rstd * w[c] + bb[c]);
}

// LayerNorm from [p][c] bf16 -> [p][c] bf16
__global__ __launch_bounds__(256) void k_ln_pc(const bf16* __restrict__ X2,
                                               const float* __restrict__ w,
                                               const float* __restrict__ bb,
                                               bf16* __restrict__ out) {
    int t = threadIdx.x;
    int p = blockIdx.x * 64 + (t >> 2), qq = t & 3;
    const bf16* row = X2 + (size_t)p * C_;
    float s = 0.f, s2 = 0.f;
    for (int c = qq * 48; c < qq * 48 + 48; c++) { float v = fb(row[c]); s += v; s2 += v * v; }
    s  += __shfl_xor(s, 1);  s  += __shfl_xor(s, 2);
    s2 += __shfl_xor(s2, 1); s2 += __shfl_xor(s2, 2);
    float mu = s / C_;
    float rstd = rsqrtf(s2 / C_ - mu * mu + 1e-5f);
    bf16* orow = out + (size_t)p * C_;
    for (int c = qq * 48; c < qq * 48 + 48; c++)
        orow[c] = tob((fb(row[c]) - mu) * rstd * w[c] + bb[c]);
}

// ---------------- 1x1 conv GEMM (global_load_lds + swizzle), BK=64 ----------------
// EPI: 1 = plain bf16 [p][Cout]
//      2 = +resid(NCHW f32)  -> bf16 [p][C_]
//      3 = +resid(bf16 [p][C_]) -> f32 NCHW
template <int BN, int EPI>
__global__ __launch_bounds__(256) void k_gemm1x1(const bf16* __restrict__ A,
                                                 const bf16* __restrict__ Wr,
                                                 const int K, const int Cout,
                                                 void* __restrict__ outp,
                                                 const void* __restrict__ resid) {
    constexpr int WN = BN / 2, FN = WN / 16, BIT = BN / 32;
    __shared__ __align__(16) bf16 As[128 * 64];
    __shared__ __align__(16) bf16 Bs[BN * 64];
    const int t = threadIdx.x;
    const int mt = blockIdx.x;
    const int n0 = blockIdx.y * BN;
    const int w = t >> 6, lane = t & 63;
    const int wm = w >> 1, wn = w & 1;
    const int g = lane >> 4, r = lane & 15;
    const int ldw = t - lane;  // w*64

    f32x4 acc[4][FN];
#pragma unroll
    for (int i = 0; i < 4; i++)
#pragma unroll
        for (int j = 0; j < FN; j++) acc[i][j] = {0.f, 0.f, 0.f, 0.f};

    const bf16* Abase = A + (size_t)mt * 128 * K;

    for (int c0 = 0; c0 < K; c0 += 64) {
#pragma unroll
        for (int it = 0; it < 4; it++) {
            int idx = it * 256 + t;
            int row = idx >> 3, sl = idx & 7;
            const char* gp = (const char*)(Abase + (size_t)row * K + c0) + ((sl ^ (row & 7)) << 4);
            gl16(gp, (char*)As + (size_t)(it * 256 + ldw) * 16);
        }
#pragma unroll
        for (int it = 0; it < BIT; it++) {
            int idx = it * 256 + t;
            int row = idx >> 3, sl = idx & 7;
            const char* gp = (const char*)(Wr + (size_t)(n0 + row) * K + c0) + ((sl ^ (row & 7)) << 4);
            gl16(gp, (char*)Bs + (size_t)(it * 256 + ldw) * 16);
        }
        __syncthreads();
#pragma unroll
        for (int ks = 0; ks < 2; ks++) {
            bf16x8v af[4], bv[FN];
#pragma unroll
            for (int fm = 0; fm < 4; fm++)
                af[fm] = lread(As, wm * 64 + fm * 16 + r, ks * 4 + g);
#pragma unroll
            for (int fn = 0; fn < FN; fn++)
                bv[fn] = lread(Bs, wn * WN + fn * 16 + r, ks * 4 + g);
#pragma unroll
            for (int fm = 0; fm < 4; fm++)
#pragma unroll
                for (int fn = 0; fn < FN; fn++)
                    acc[fm][fn] = __builtin_amdgcn_mfma_f32_16x16x32_bf16(af[fm], bv[fn], acc[fm][fn], 0, 0, 0);
        }
        __syncthreads();
    }

    const int b = mt >> 7, y = mt & 127;
#pragma unroll
    for (int fm = 0; fm < 4; fm++)
#pragma unroll
        for (int fn = 0; fn < FN; fn++)
#pragma unroll
            for (int reg = 0; reg < 4; reg++) {
                int xl = wm * 64 + fm * 16 + g * 4 + reg;
                int co = n0 + wn * WN + fn * 16 + r;
                float v = acc[fm][fn][reg];
                if constexpr (EPI == 1) {
                    ((bf16*)outp)[((size_t)mt * 128 + xl) * Cout + co] = tob(v);
                } else if constexpr (EPI == 2) {
                    v += ((const float*)resid)[((size_t)(b * C_ + co)) * HW_ + y * 128 + xl];
                    ((bf16*)outp)[((size_t)mt * 128 + xl) * C_ + co] = tob(v);
                } else {
                    v += fb(((const bf16*)resid)[((size_t)mt * 128 + xl) * C_ + co]);
                    ((float*)outp)[((size_t)(b * C_ + co)) * HW_ + y * 128 + xl] = v;
                }
            }
}

// ---------------- 3x3 full conv implicit GEMM (global_load_lds + swizzle + zero page) --
// A tile: 160 rows x 64ch (rows 1..128 = x 0..127; rows 0,129+ = zero page)
// B tile: BN rows x 64ch, staged per kx. EPI: 0 = plain bf16, 1 = GELU bf16
template <int BN, int EPI>
__global__ __launch_bounds__(256) void k_gemm3x3(const bf16* __restrict__ A,
                                                 const bf16* __restrict__ Wr,
                                                 const int Cin, const int Cout,
                                                 bf16* __restrict__ outp,
                                                 const char* __restrict__ zpage) {
    constexpr int WN = BN / 2, FN = WN / 16, BIT = BN / 32;
    __shared__ __align__(16) bf16 As[160 * 64];
    __shared__ __align__(16) bf16 Bs[BN * 64];
    const int t = threadIdx.x;
    const int mt = blockIdx.x;
    const int n0 = blockIdx.y * BN;
    const int b = mt >> 7, y = mt & 127;
    const int w = t >> 6, lane = t & 63;
    const int wm = w >> 1, wn = w & 1;
    const int g = lane >> 4, r = lane & 15;
    const int ldw = t - lane;

    f32x4 acc[4][FN];
#pragma unroll
    for (int i = 0; i < 4; i++)
#pragma unroll
        for (int j = 0; j < FN; j++) acc[i][j] = {0.f, 0.f, 0.f, 0.f};

    for (int ky = 0; ky < 3; ky++) {
        const int yy = y + ky - 1;
        if (yy < 0 || yy > 127) continue;   // block-uniform
        const bf16* Ab = A + ((size_t)b * HW_ + (size_t)yy * 128) * Cin;
        for (int c0 = 0; c0 < Cin; c0 += 64) {
            for (int kx = 0; kx < 3; kx++) {
                if (kx == 0) {
#pragma unroll
                    for (int it = 0; it < 5; it++) {
                        int idx = it * 256 + t;
                        int row = idx >> 3, sl = idx & 7;
                        int so = (sl ^ (row & 7)) << 4;
                        const char* gp = (row >= 1 && row <= 128)
                            ? (const char*)(Ab + (size_t)(row - 1) * Cin + c0) + so
                            : zpage + so;
                        gl16(gp, (char*)As + (size_t)(it * 256 + ldw) * 16);
                    }
                }
                const bf16* Wb = Wr + (size_t)(ky * 3 + kx) * Cout * Cin;
#pragma unroll
                for (int it = 0; it < BIT; it++) {
                    int idx = it * 256 + t;
                    int row = idx >> 3, sl = idx & 7;
                    const char* gp = (const char*)(Wb + (size_t)(n0 + row) * Cin + c0) + ((sl ^ (row & 7)) << 4);
                    gl16(gp, (char*)Bs + (size_t)(it * 256 + ldw) * 16);
                }
                __syncthreads();
#pragma unroll
                for (int ks = 0; ks < 2; ks++) {
                    bf16x8v af[4], bv[FN];
#pragma unroll
                    for (int fm = 0; fm < 4; fm++)
                        af[fm] = lread(As, wm * 64 + fm * 16 + r + kx, ks * 4 + g);
#pragma unroll
                    for (int fn = 0; fn < FN; fn++)
                        bv[fn] = lread(Bs, wn * WN + fn * 16 + r, ks * 4 + g);
#pragma unroll
                    for (int fm = 0; fm < 4; fm++)
#pragma unroll
                        for (int fn = 0; fn < FN; fn++)
                            acc[fm][fn] = __builtin_amdgcn_mfma_f32_16x16x32_bf16(af[fm], bv[fn], acc[fm][fn], 0, 0, 0);
                }
                __syncthreads();
            }
        }
    }
#pragma unroll
    for (int fm = 0; fm < 4; fm++)
#pragma unroll
        for (int fn = 0; fn < FN; fn++)
#pragma unroll
            for (int reg = 0; reg < 4; reg++) {
                int xl = wm * 64 + fm * 16 + g * 4 + reg;
                int co = n0 + wn * WN + fn * 16 + r;
                float v = acc[fm][fn][reg];
                if constexpr (EPI == 1) v = 0.5f * v * (1.0f + erff(v * 0.70710678118654752f));
                outp[((size_t)mt * 128 + xl) * Cout + co] = tob(v);
            }
}

// ---------------- depthwise 3x3: weights in LDS->VGPR, 16 x-positions per thread -------
// grid (256 = b*128+y, 2 = k/v half), block 192: c8h = t%24, xg = t/24
__global__ __launch_bounds__(192) void k_dwconv2(const bf16* __restrict__ kv,
                                                 const float* __restrict__ wdw,
                                                 bf16* __restrict__ kout,
                                                 bf16* __restrict__ vout) {
    __shared__ float wlds[1728];  // this half's 192 ch x 9 taps
    const int t = threadIdx.x;
    const int row = blockIdx.x;
    const int z = blockIdx.y;
    const int b = row >> 7, y = row & 127;
    for (int i = t; i < 432; i += 192)
        ((float4*)wlds)[i] = ((const float4*)(wdw + (size_t)z * 1728))[i];
    __syncthreads();
    const int c8h = t % 24, xg = t / 24;  // xg 0..7
    const int cbase = z * C_ + c8h * 8;
    float wreg[9][8];
#pragma unroll
    for (int tap = 0; tap < 9; tap++)
#pragma unroll
        for (int j = 0; j < 8; j++) wreg[tap][j] = wlds[(c8h * 8 + j) * 9 + tap];

    bf16* outb = (z == 0 ? kout : vout) + (size_t)(b * HW_ + y * 128) * C_ + c8h * 8;
    const uint4 zero4 = make_uint4(0u, 0u, 0u, 0u);
    for (int i = 0; i < 16; i++) {
        int x = xg + 8 * i;
        float acc[8];
#pragma unroll
        for (int j = 0; j < 8; j++) acc[j] = 0.f;
#pragma unroll
        for (int ky = 0; ky < 3; ky++) {
            int yy = y + ky - 1;
            if (yy < 0 || yy > 127) continue;   // block-uniform
            const bf16* rb = kv + ((size_t)b * HW_ + (size_t)yy * 128) * C2_ + cbase;
#pragma unroll
            for (int kx = 0; kx < 3; kx++) {
                int xx = x + kx - 1;
                uint4 vv = (xx >= 0 && xx <= 127) ? *(const uint4*)(rb + (size_t)xx * C2_) : zero4;
                const bf16* pv = (const bf16*)&vv;
#pragma unroll
                for (int j = 0; j < 8; j++)
                    acc[j] += fb(pv[j]) * wreg[ky * 3 + kx][j];
            }
        }
        union { bf16 h[8]; uint4 u; } ov;
#pragma unroll
        for (int j = 0; j < 8; j++) ov.h[j] = tob(acc[j]);
        *(uint4*)(outb + (size_t)x * C_) = ov.u;
    }
}

// ---------------- deterministic per-(sel,b,c) sum-of-squares partials (vectorized) -----
// grid (64 chunks, b, sel), block 192: c8 = t%24, slot = t/24; chunk = 256 positions
__global__ __launch_bounds__(192) void k_ssqpart(const bf16* __restrict__ q,
                                                 const bf16* __restrict__ k,
                                                 float* __restrict__ ssq) {
    __shared__ float red[192][8];
    int t = threadIdx.x;
    int c8 = t % 24, slot = t / 24;
    int ch = blockIdx.x, b = blockIdx.y, sel = blockIdx.z;
    const bf16* src = (sel ? k : q) + ((size_t)b * HW_ + ch * 256) * C_ + c8 * 8;
    float s[8];
#pragma unroll
    for (int j = 0; j < 8; j++) s[j] = 0.f;
    for (int i = slot; i < 256; i += 8) {
        uint4 v = *(const uint4*)(src + (size_t)i * C_);
        const bf16* pv = (const bf16*)&v;
#pragma unroll
        for (int j = 0; j < 8; j++) { float x = fb(pv[j]); s[j] += x * x; }
    }
#pragma unroll
    for (int j = 0; j < 8; j++) red[t][j] = s[j];
    __syncthreads();
    if (slot == 0) {
        float o[8];
#pragma unroll
        for (int j = 0; j < 8; j++) o[j] = 0.f;
        for (int ss = 0; ss < 8; ss++)
#pragma unroll
            for (int j = 0; j < 8; j++) o[j] += red[c8 + 24 * ss][j];
        float* dst = ssq + (((size_t)(sel * 2 + b)) * 64 + ch) * C_ + c8 * 8;
#pragma unroll
        for (int j = 0; j < 8; j++) dst[j] = o[j];
    }
}

__global__ void k_inv(const float* __restrict__ ssq, float* __restrict__ inv) {
    int i = blockIdx.x * 256 + threadIdx.x;
    if (i >= 768) return;
    int sb = i / C_, c = i % C_;
    float s = 0.f;
    for (int ch = 0; ch < 64; ch++) s += ssq[((size_t)sb * 64 + ch) * C_ + c];
    inv[i] = 1.f / fmaxf(sqrtf(s), 1e-12f);
}

// ---------------- S partials: per (b,hd,chunk) 48x48 over 1024 positions ----------------
__global__ __launch_bounds__(256) void k_qk(const bf16* __restrict__ q,
                                            const bf16* __restrict__ k,
                                            float* __restrict__ Spart) {
    __shared__ float qs[64][49];
    __shared__ float ks[64][49];
    int t = threadIdx.x;
    int ch = blockIdx.x, hd = blockIdx.y, b = blockIdx.z;
    int i0 = (t >> 4) * 3, j0 = (t & 15) * 3;
    float acc[3][3];
#pragma unroll
    for (int a = 0; a < 3; a++)
#pragma unroll
        for (int c = 0; c < 3; c++) acc[a][c] = 0.f;

    for (int sub = 0; sub < 16; sub++) {
        size_t rbase = ((size_t)b * HW_ + ch * 1024 + sub * 64) * C_ + hd * 48;
        for (int i = t; i < 64 * 6; i += 256) {
            int row = i / 6, oc = i % 6;
            uint4 v = *(const uint4*)(q + rbase + (size_t)row * C_ + oc * 8);
            const bf16* pv = (const bf16*)&v;
#pragma unroll
            for (int j = 0; j < 8; j++) qs[row][oc * 8 + j] = fb(pv[j]);
            uint4 v2 = *(const uint4*)(k + rbase + (size_t)row * C_ + oc * 8);
            const bf16* pv2 = (const bf16*)&v2;
#pragma unroll
            for (int j = 0; j < 8; j++) ks[row][oc * 8 + j] = fb(pv2[j]);
        }
        __syncthreads();
        for (int p = 0; p < 64; p++) {
            float a0 = qs[p][i0], a1 = qs[p][i0 + 1], a2 = qs[p][i0 + 2];
            float b0 = ks[p][j0], b1 = ks[p][j0 + 1], b2 = ks[p][j0 + 2];
            acc[0][0] += a0 * b0; acc[0][1] += a0 * b1; acc[0][2] += a0 * b2;
            acc[1][0] += a1 * b0; acc[1][1] += a1 * b1; acc[1][2] += a1 * b2;
            acc[2][0] += a2 * b0; acc[2][1] += a2 * b1; acc[2][2] += a2 * b2;
        }
        __syncthreads();
    }
    float* dst = Spart + (((size_t)(b * 4 + hd)) * 16 + ch) * 2304;
#pragma unroll
    for (int a = 0; a < 3; a++)
#pragma unroll
        for (int c = 0; c < 3; c++) dst[(i0 + a) * 48 + (j0 + c)] = acc[a][c];
}

__global__ void k_softmax(const float* __restrict__ Spart, const float* __restrict__ invq,
                          const float* __restrict__ invk, const float* __restrict__ temp,
                          float* __restrict__ attn) {
    int t = threadIdx.x;
    if (t >= 48) return;
    int hd = blockIdx.x, b = blockIdx.y;
    const float* base = Spart + ((size_t)(b * 4 + hd)) * 16 * 2304;
    float qi = invq[b * C_ + hd * 48 + t];
    float tp = temp[hd];
    float row[48];
    float mx = -1e30f;
    for (int j = 0; j < 48; j++) {
        float s = 0.f;
        for (int ch = 0; ch < 16; ch++) s += base[ch * 2304 + t * 48 + j];
        s *= qi * invk[b * C_ + hd * 48 + j] * tp;
        row[j] = s;
        mx = fmaxf(mx, s);
    }
    float sum = 0.f;
    for (int j = 0; j < 48; j++) { row[j] = expf(row[j] - mx); sum += row[j]; }
    float is = 1.f / sum;
    for (int j = 0; j < 48; j++)
        attn[(((size_t)(b * 4 + hd)) * 48 + t) * 48 + j] = row[j] * is;
}

// ---------------- out = attn @ v  (per position, per head) ----------------
__global__ __launch_bounds__(256) void k_av(const float* __restrict__ attn,
                                            const bf16* __restrict__ v,
                                            bf16* __restrict__ out) {
    __shared__ float As[4 * 48 * 48];
    int t = threadIdx.x;
    int b = blockIdx.y;
    for (int i = t; i < 9216; i += 256) As[i] = attn[(size_t)b * 9216 + i];
    __syncthreads();
    int p = blockIdx.x * 64 + (t >> 2);
    int hd = t & 3;
    size_t row = (size_t)b * HW_ + p;
    const float* am = As + hd * 2304;
    float acc[48];
#pragma unroll
    for (int i = 0; i < 48; i++) acc[i] = 0.f;
#pragma unroll
    for (int jo = 0; jo < 6; jo++) {
        uint4 vv = *(const uint4*)(v + row * C_ + hd * 48 + jo * 8);
        const bf16* pv = (const bf16*)&vv;
#pragma unroll
        for (int jj = 0; jj < 8; jj++) {
            float vj = fb(pv[jj]);
            int j = jo * 8 + jj;
#pragma unroll
            for (int i = 0; i < 48; i++) acc[i] += am[i * 48 + j] * vj;
        }
    }
#pragma unroll
    for (int io = 0; io < 6; io++) {
        union { bf16 h[8]; uint4 u; } ov;
#pragma unroll
        for (int jj = 0; jj < 8; jj++) ov.h[jj] = tob(acc[io * 8 + jj]);
        *(uint4*)(out + row * C_ + hd * 48 + io * 8) = ov.u;
    }
}

// =====================================================================================
extern "C" void kernel_launch(void* const* d_in, const int* in_sizes, int n_in,
                              void* d_out, int out_size, void* d_ws, size_t ws_size,
                              hipStream_t stream) {
    const float* x     = (const float*)d_in[0];
    const float* illum = (const float*)d_in[1];
    const float* ln1w  = (const float*)d_in[2];
    const float* ln1b  = (const float*)d_in[3];
    const float* lnLw  = (const float*)d_in[4];
    const float* lnLb  = (const float*)d_in[5];
    const float* ln2w  = (const float*)d_in[6];
    const float* ln2b  = (const float*)d_in[7];
    const float* qw    = (const float*)d_in[8];
    const float* qdww  = (const float*)d_in[9];
    const float* kvw   = (const float*)d_in[10];
    const float* kvdww = (const float*)d_in[11];
    const float* temp  = (const float*)d_in[12];
    const float* projw = (const float*)d_in[13];
    const float* pinw  = (const float*)d_in[14];
    const float* dww   = (const float*)d_in[15];
    const float* poutw = (const float*)d_in[16];

    char* ws = (char*)d_ws;
    // ---- small region: weights + attention scratch ----
    bf16*  Wq1   = (bf16*)(ws + 0);         //   73,728
    bf16*  Wkv   = (bf16*)(ws + 73728);     //  147,456
    bf16*  Wqdw  = (bf16*)(ws + 221184);    //  663,552
    bf16*  Wproj = (bf16*)(ws + 884736);    //   73,728
    bf16*  Wpin  = (bf16*)(ws + 958464);    //  196,608
    bf16*  Wdw   = (bf16*)(ws + 1155072);   // 4,718,592
    bf16*  Wpout = (bf16*)(ws + 5873664);   //  196,608
    float* Spart = (float*)(ws + 6070272);  // 1,179,648
    float* attn  = (float*)(ws + 7249920);  //   73,728
    float* ssq   = (float*)(ws + 7323648);  //  196,608
    float* invv  = (float*)(ws + 7520256);  //    3,072
    char*  zpage = (char*)(ws + 7523328);   //    4,096 zero page for border lanes
    // ---- activation arena: slots of u=12,582,912 bytes, lifetime-packed ----
    const size_t A0 = 7527424, u = 12582912;
    bf16* xn    = (bf16*)(ws + A0 + 0 * u);   // [LN1, kv-gemm]
    bf16* iln   = (bf16*)(ws + A0 + 1 * u);   // [LNL, q-1x1]
    bf16* qtmp  = (bf16*)(ws + A0 + 2 * u);   // [q-1x1, q-3x3]
    bf16* qb    = (bf16*)(ws + A0 + 1 * u);   // [q-3x3, qk]     (over iln)
    bf16* kvtmp = (bf16*)(ws + A0 + 2 * u);   // [kv-gemm, dwconv] 2 slots (over qtmp)
    bf16* kb    = (bf16*)(ws + A0 + 0 * u);   // [dwconv, qk]    (over xn)
    bf16* vb    = (bf16*)(ws + A0 + 4 * u);   // [dwconv, av]
    bf16* outa  = (bf16*)(ws + A0 + 2 * u);   // [av, proj]      (over kvtmp-lo)
    bf16* x2    = (bf16*)(ws + A0 + 0 * u);   // [proj, pout]    (over kb)
    bf16* xn2   = (bf16*)(ws + A0 + 3 * u);   // [LN2, pin]      (over kvtmp-hi)
    bf16* fbuf  = (bf16*)(ws + A0 + 4 * u);   // [pin, dw3x3]  33,554,432 (over vb)
    bf16* gbuf  = (bf16*)(ws + A0 + 1 * u);   // [dw3x3, pout] 33,554,432 (slots 1-3)
    // total = A0 + 4u + 33,554,432 = 91,413,504 bytes (~87.2 MB)

    hipMemsetAsync(zpage, 0, 4096, stream);

    // 0) weight repacks (bf16, zero-padded channels)
    k_repack1<<<(192 * 192 + 255) / 256, 256, 0, stream>>>(qw, Wq1, 192, 192, 192, 192);
    k_repack1<<<(384 * 192 + 255) / 256, 256, 0, stream>>>(kvw, Wkv, 384, 192, 384, 192);
    k_repack3<<<(9 * 192 * 192 + 255) / 256, 256, 0, stream>>>(qdww, Wqdw, 192, 192, 192, 192);
    k_repack1<<<(192 * 192 + 255) / 256, 256, 0, stream>>>(projw, Wproj, 192, 192, 192, 192);
    k_repack1<<<(512 * 192 + 255) / 256, 256, 0, stream>>>(pinw, Wpin, 510, 192, 512, 192);
    k_repack3<<<(9 * 512 * 512 + 255) / 256, 256, 0, stream>>>(dww, Wdw, 510, 510, 512, 512);
    k_repack1<<<(192 * 512 + 255) / 256, 256, 0, stream>>>(poutw, Wpout, 192, 510, 192, 512);

    // 1) LayerNorms
    k_ln_nchw<<<512, 256, 0, stream>>>(x, ln1w, ln1b, xn);
    k_ln_nchw<<<512, 256, 0, stream>>>(illum, lnLw, lnLb, iln);

    // 2) q = 1x1(iln) ; then full 3x3 -> qb
    k_gemm1x1<96, 1><<<dim3(256, 2), 256, 0, stream>>>(iln, Wq1, 192, 192, qtmp, nullptr);
    k_gemm3x3<96, 0><<<dim3(256, 2), 256, 0, stream>>>(qtmp, Wqdw, 192, 192, qb, zpage);

    // 3) kv = 1x1(xn) ; depthwise 3x3 -> kb, vb
    k_gemm1x1<128, 1><<<dim3(256, 3), 256, 0, stream>>>(xn, Wkv, 192, 384, kvtmp, nullptr);
    k_dwconv2<<<dim3(256, 2), 192, 0, stream>>>(kvtmp, kvdww, kb, vb);

    // 4) attention
    k_ssqpart<<<dim3(64, 2, 2), 192, 0, stream>>>(qb, kb, ssq);
    k_inv<<<3, 256, 0, stream>>>(ssq, invv);
    k_qk<<<dim3(16, 4, 2), 256, 0, stream>>>(qb, kb, Spart);
    k_softmax<<<dim3(4, 2), 64, 0, stream>>>(Spart, invv, invv + 384, temp, attn);
    k_av<<<dim3(256, 2), 256, 0, stream>>>(attn, vb, outa);

    // 5) x2 = x + proj(out)   (bf16 residual stream)
    k_gemm1x1<96, 2><<<dim3(256, 2), 256, 0, stream>>>(outa, Wproj, 192, 192, x2, x);

    // 6) FFN
    k_ln_pc<<<512, 256, 0, stream>>>(x2, ln2w, ln2b, xn2);
    k_gemm1x1<128, 1><<<dim3(256, 4), 256, 0, stream>>>(xn2, Wpin, 192, 512, fbuf, nullptr);
    k_gemm3x3<128, 1><<<dim3(256, 4), 256, 0, stream>>>(fbuf, Wdw, 512, 512, gbuf, zpage);
    k_gemm1x1<96, 3><<<dim3(256, 2), 256, 0, stream>>>(gbuf, Wpout, 512, 192, d_out, x2);
}